// Round 18
// baseline (111.785 us; speedup 1.0000x reference)
//
#include <hip/hip_runtime.h>
#include <math.h>

#define NN 4096
#define DD 64
#define NSPLIT 64
#define JW 64
#define NUNITS 5121u

typedef _Float16 half8 __attribute__((ext_vector_type(8)));
typedef float f32x4 __attribute__((ext_vector_type(4)));

__device__ __forceinline__ unsigned sxu(unsigned v, int o){
  return (unsigned)__shfl_xor((int)v, o, 64);
}
__device__ __forceinline__ unsigned umn(unsigned a, unsigned b){ return a<b?a:b; }
__device__ __forceinline__ unsigned umx(unsigned a, unsigned b){ return a<b?b:a; }
__device__ __forceinline__ unsigned med3u(unsigned a, unsigned b, unsigned c){
  unsigned r; asm("v_med3_u32 %0, %1, %2, %3" : "=v"(r) : "v"(a), "v"(b), "v"(c)); return r;
}
__device__ __forceinline__ unsigned min3u(unsigned a, unsigned b, unsigned c){
  unsigned r; asm("v_min3_u32 %0, %1, %2, %3" : "=v"(r) : "v"(a), "v"(b), "v"(c)); return r;
}

// key = (quantized m << 12) | j ; m=sqj-2dot, q=(m+256)*2048 clamped to 20 bits
__device__ __forceinline__ unsigned packkey32(float m, int j){
  float q = fmaf(m, 2048.f, 524288.f);
  q = fminf(fmaxf(q, 0.f), 1048575.f);
  return (((unsigned)q) << 12) | (unsigned)j;
}

// sorted-5 insert via med3: b0'=min(k,b0); bi'=med3(k,b[i-1],b[i])
__device__ __forceinline__ void ins5u(unsigned k, unsigned b[5]){
  unsigned nb0 = umn(k, b[0]);
  b[4] = med3u(k, b[3], b[4]);
  b[3] = med3u(k, b[2], b[3]);
  b[2] = med3u(k, b[1], b[2]);
  b[1] = med3u(k, b[0], b[1]);
  b[0] = nb0;
}

// butterfly merge stage across lanes: sorted-5 + partner sorted-5 -> sorted-5
__device__ __forceinline__ void mergeStage32(unsigned b[5], int st){
  unsigned p0=sxu(b[0],st),p1=sxu(b[1],st),p2=sxu(b[2],st),p3=sxu(b[3],st),p4=sxu(b[4],st);
  unsigned o0=umn(b[0],p0);
  unsigned o1=min3u(b[1],p1, umx(b[0],p0));
  unsigned o2=min3u(b[2],p2, umn(umx(b[0],p1),umx(b[1],p0)));
  unsigned o3=min3u(b[3],p3, min3u(umx(b[0],p2), umx(b[1],p1), umx(b[2],p0)));
  unsigned o4=min3u(b[4],p4, umn(umn(umx(b[0],p3),umx(b[1],p2)),
                                 umn(umx(b[2],p1),umx(b[3],p0))));
  b[0]=o0;b[1]=o1;b[2]=o2;b[3]=o3;b[4]=o4;
}

// local merge of two sorted-5 lists -> sorted-5
__device__ __forceinline__ void mergeLocal32(const unsigned a[5], const unsigned c[5], unsigned b[5]){
  b[0]=umn(a[0],c[0]);
  b[1]=min3u(a[1],c[1], umx(a[0],c[0]));
  b[2]=min3u(a[2],c[2], umn(umx(a[0],c[1]),umx(a[1],c[0])));
  b[3]=min3u(a[3],c[3], min3u(umx(a[0],c[2]), umx(a[1],c[1]), umx(a[2],c[0])));
  b[4]=min3u(a[4],c[4], umn(umn(umx(a[0],c[3]),umx(a[1],c[2])),
                            umn(umx(a[2],c[1]),umx(a[3],c[0]))));
}

// ---- fused pre: sq, split-f16 hi/lo, per-block partial colsum + max; resets work counter ----
__global__ __launch_bounds__(256) void k_prec(const float* __restrict__ x,
                      float* __restrict__ sq,
                      _Float16* __restrict__ xh, _Float16* __restrict__ xl,
                      float* __restrict__ msum_part, float* __restrict__ maxsq_part,
                      unsigned* __restrict__ counter){
  __shared__ float part[4][64];
  __shared__ float mxp[4];
  const int w = threadIdx.x>>6, lane = threadIdx.x&63;
  const int n0 = blockIdx.x*16 + w*4;
  if(blockIdx.x==0 && threadIdx.x==0) counter[0] = 0u;
  float v0 = x[(size_t)(n0+0)*DD + lane];
  float v1 = x[(size_t)(n0+1)*DD + lane];
  float v2 = x[(size_t)(n0+2)*DD + lane];
  float v3 = x[(size_t)(n0+3)*DD + lane];
  float s0=v0*v0, s1=v1*v1, s2=v2*v2, s3=v3*v3;
#pragma unroll
  for(int o=1;o<64;o<<=1){
    s0 += __shfl_xor(s0,o,64); s1 += __shfl_xor(s1,o,64);
    s2 += __shfl_xor(s2,o,64); s3 += __shfl_xor(s3,o,64);
  }
  float vv[4] = {v0,v1,v2,v3};
  float ss[4] = {s0,s1,s2,s3};
#pragma unroll
  for(int q=0;q<4;q++){
    float v = vv[q];
    _Float16 h = (_Float16)v;
    _Float16 l = (_Float16)(v - (float)h);
    xh[(size_t)(n0+q)*DD+lane] = h;
    xl[(size_t)(n0+q)*DD+lane] = l;
    if(lane==0) sq[n0+q]=ss[q];
  }
  if(lane==0) mxp[w] = fmaxf(fmaxf(s0,s1), fmaxf(s2,s3));
  part[w][lane] = v0+v1+v2+v3; __syncthreads();
  if(w==0){
    msum_part[blockIdx.x*64 + lane] = part[0][lane]+part[1][lane]+part[2][lane]+part[3][lane];
    if(lane==0) maxsq_part[blockIdx.x] = fmaxf(fmaxf(mxp[0],mxp[1]), fmaxf(mxp[2],mxp[3]));
  }
}

// 6-MFMA split-f16 Gram for one 16x16 tile: returns row-dots for this lane
__device__ __forceinline__ f32x4 gram6(const half8 J[4],
    half8 Ih0, half8 Ih1, half8 Il0, half8 Il1){
  const f32x4 z = {0.f,0.f,0.f,0.f};
  f32x4 a1 = __builtin_amdgcn_mfma_f32_16x16x32_f16(J[0], Ih0, z, 0,0,0);
  f32x4 a2 = __builtin_amdgcn_mfma_f32_16x16x32_f16(J[2], Ih0, z, 0,0,0);
  a1 = __builtin_amdgcn_mfma_f32_16x16x32_f16(J[1], Ih1, a1, 0,0,0);
  a2 = __builtin_amdgcn_mfma_f32_16x16x32_f16(J[3], Ih1, a2, 0,0,0);
  a1 = __builtin_amdgcn_mfma_f32_16x16x32_f16(J[0], Il0, a1, 0,0,0);
  a1 = __builtin_amdgcn_mfma_f32_16x16x32_f16(J[1], Il1, a1, 0,0,0);
  return a1 + a2;
}

// ======== MEGA (persistent work-queue): unit 0 = stats reduce; t%5==0 sparse, else knng ========
// Branch LDS union (16 KB): knng jHi[8KB]|jLo[8KB]; sparse nbr[2KB]|Sval[2KB]; reducer rr|rm
__global__ __launch_bounds__(256, 8) void k_mega(
    const float* __restrict__ x, const float* __restrict__ A,
    const float* __restrict__ sq,
    const _Float16* __restrict__ xh, const _Float16* __restrict__ xl,
    unsigned* __restrict__ cand, unsigned* __restrict__ counter,
    const float* __restrict__ msum_part, const float* __restrict__ maxsq_part,
    float* __restrict__ msum, float* __restrict__ max_sq, float* __restrict__ deg_out,
    float* __restrict__ o_te, float* __restrict__ o_ent,
    float* __restrict__ o_if, float* __restrict__ o_st, float* __restrict__ o_cv)
{
  __shared__ __align__(16) char smem[16384];
  __shared__ unsigned s_u;
  const int tid = threadIdx.x;
  const int w = tid>>6, lane = tid&63;

  for(;;){
    if(tid==0) s_u = atomicAdd(counter, 1u);
    __syncthreads();
    const unsigned u = s_u;
    if(u >= NUNITS) break;

    if(u == 0){
      float* rr = (float*)smem;              // [4][64]
      float* rm = (float*)(smem + 1024);     // [4]
      float s = 0.f;
      for(int p=w; p<256; p+=4) s += msum_part[p*64 + lane];
      rr[w*64 + lane] = s;
      float m = maxsq_part[w*64 + lane];
#pragma unroll
      for(int o=1;o<64;o<<=1) m = fmaxf(m, __shfl_xor(m,o,64));
      if(lane==0) rm[w] = m;
      __syncthreads();
      if(w==0){
        msum[lane] = rr[0*64+lane]+rr[1*64+lane]+rr[2*64+lane]+rr[3*64+lane];
        if(lane==0) max_sq[0] = fmaxf(fmaxf(rm[0],rm[1]), fmaxf(rm[2],rm[3]));
      }
      __syncthreads();
      continue;
    }

    const int t = (int)u - 1;
    if(t % 5 == 0){
      // ================= sparse branch: wave per node, ballot compaction =================
      int*   nbrw  = (int*)smem + w*128;             // [128]
      float* Svalw = (float*)(smem + 2048) + w*128;  // [128]
      const int i = (t/5)*4 + w;
      const float xid = x[(size_t)i*DD + lane];
      const float sqi = sq[i];
      const float eni = sqrtf(sqi);
      const float4* A4 = (const float4*)(A + (size_t)i*NN);
      const unsigned long long below = (1ull << lane) - 1ull;

      int base = 0;
#define COMPACT(VAL, JJ) { \
      bool p_ = (VAL) > 0.f; \
      unsigned long long m_ = __ballot(p_); \
      int ofs_ = base + (int)__popcll(m_ & below); \
      if(p_ && ofs_ < 128) nbrw[ofs_] = (JJ); \
      base += (int)__popcll(m_); \
    }
      for(int ch=0; ch<4; ++ch){
        float4 av[4];
#pragma unroll
        for(int qq=0; qq<4; ++qq) av[qq] = A4[lane + 64*(ch*4+qq)];
#pragma unroll
        for(int qq=0; qq<4; ++qq){
          int jb = 4*(lane + 64*(ch*4+qq));
          COMPACT(av[qq].x, jb+0);
          COMPACT(av[qq].y, jb+1);
          COMPACT(av[qq].z, jb+2);
          COMPACT(av[qq].w, jb+3);
        }
      }
#undef COMPACT
      const int deg = base;

      const float degf = (float)deg;
      const int dmax = min(deg, 128);
      float nb_d=0.f, ex2_d=0.f, s_d=0.f, ssq=0.f;

      for(int c0=0; c0<dmax; c0+=8){
        int jq[8]; float aq[8], qq[8];
#pragma unroll
        for(int q=0;q<8;q++) jq[q] = nbrw[min(c0+q, dmax-1)];
#pragma unroll
        for(int q=0;q<8;q++) aq[q] = x[(size_t)jq[q]*DD + lane];
#pragma unroll
        for(int q=0;q<8;q++) qq[q] = sq[jq[q]];
        asm volatile("" :: "v"(aq[0]), "v"(aq[1]), "v"(aq[2]), "v"(aq[3]),
                           "v"(aq[4]), "v"(aq[5]), "v"(aq[6]), "v"(aq[7]));
        float p[8];
#pragma unroll
        for(int q=0;q<8;q++) p[q] = xid*aq[q];
#pragma unroll
        for(int o=1;o<64;o<<=1){
#pragma unroll
          for(int q=0;q<8;q++) p[q] += __shfl_xor(p[q],o,64);
        }
#pragma unroll
        for(int q=0;q<8;q++){
          const bool valid = (c0+q) < deg;
          float c2 = fmaxf(sqi + qq[q] - 2.0f*p[q], 1e-12f);
          float inv = 1.0f/fmaxf(sqrtf(c2), 1e-8f);
          nb_d  += valid ? aq[q] : 0.f;
          ex2_d += valid ? aq[q]*aq[q] : 0.f;
          s_d   += valid ? (aq[q]-xid)*inv : 0.f;
          ssq   += valid ? c2*inv*inv : 0.f;
          if(valid && lane==q) Svalw[c0+q] = p[q]/(eni*sqrtf(qq[q]));
        }
      }

      float t0 = xid*nb_d;
      float m1 = nb_d/degf;
      float t1 = (ex2_d - degf*m1*m1)/(degf-1.0f);
      float t2 = s_d*s_d;
      float t3 = 0.f, t4 = 0.f;
      for(int s=lane; s<dmax; s+=64){ float v=Svalw[s]; t3 += expf(v); t4 += v; }
#pragma unroll
      for(int o=1;o<64;o<<=1){
        t0 += __shfl_xor(t0,o,64); t1 += __shfl_xor(t1,o,64); t2 += __shfl_xor(t2,o,64);
        t3 += __shfl_xor(t3,o,64); t4 += __shfl_xor(t4,o,64);
      }
      const float pot = t0, varm = t1*(1.0f/DD), s2 = t2, se = t3, ms = t4/degf;

      float e0=0.f, e1=0.f;
      const float inv_se = 1.0f/se;
      for(int s=lane; s<dmax; s+=64){
        float v = Svalw[s];
        float pp = expf(v)*inv_se;
        e0 -= pp*logf(pp + 1e-8f);
        float dv = v-ms; e1 += dv*dv;
      }
#pragma unroll
      for(int o=1;o<64;o<<=1){ e0 += __shfl_xor(e0,o,64); e1 += __shfl_xor(e1,o,64); }

      if(lane==0){
        o_te[i]  = sqi - pot/(degf + 1e-8f);
        o_ent[i] = e0;
        o_if[i]  = e1/(degf-1.0f);
        o_st[i]  = 1.0f/(1.0f + varm);
        o_cv[i]  = 1.0f - (s2 - ssq)/(degf*(degf-1.0f));
        deg_out[i] = degf;
      }
    } else {
      // ========== knng branch: 64 j / unit, single staged chunk, 1 barrier ==========
      _Float16* jHi = (_Float16*)smem;            // 512*8 halves = 8KB
      _Float16* jLo = (_Float16*)(smem + 8192);   // 8KB
      const int kid = (t/5)*4 + (t%5) - 1;           // 0..4095
      const int split = kid & (NSPLIT-1);            // 0..63
      const int strip = (kid >> 6)*4 + w;            // 0..255
      const int ibase = strip*16, j0 = split*JW;
      const int col = lane & 15, kg = lane >> 4;
      const int vo = col*DD + kg*8;
      const int myi = ibase + col;

      // stage 64 j-rows hi/lo into LDS; linear dest,
      // source pre-swizzled (granule g: row=g>>3, chunk=(g&7)^(row&7))
#pragma unroll
      for(int q_=0;q_<2;q_++){
        int g_ = q_*256 + tid;
        int r_ = g_ >> 3;
        int c_ = (g_ & 7) ^ (r_ & 7);
        const _Float16* sH_ = xh + (size_t)(j0 + r_)*DD + c_*8;
        const _Float16* sL_ = xl + (size_t)(j0 + r_)*DD + c_*8;
        __builtin_amdgcn_global_load_lds(
          (const __attribute__((address_space(1))) unsigned int*)sH_,
          (__attribute__((address_space(3))) unsigned int*)(jHi + g_*8), 16, 0, 0);
        __builtin_amdgcn_global_load_lds(
          (const __attribute__((address_space(1))) unsigned int*)sL_,
          (__attribute__((address_space(3))) unsigned int*)(jLo + g_*8), 16, 0, 0);
      }

      // I-fragments from global (overlap with async staging)
      const _Float16* pih = xh + (size_t)ibase*DD + vo;
      const _Float16* pil = xl + (size_t)ibase*DD + vo;
      const half8 Ih0 = *(const half8*)(pih);
      const half8 Ih1 = *(const half8*)(pih+32);
      const half8 Il0 = *(const half8*)(pil);
      const half8 Il1 = *(const half8*)(pil+32);

      const int jb0 = j0 + kg*4;
      float4 sq0 = *(const float4*)(sq + jb0);
      float4 sq1 = *(const float4*)(sq + jb0 + 16);
      float4 sq2 = *(const float4*)(sq + jb0 + 32);
      float4 sq3 = *(const float4*)(sq + jb0 + 48);

      unsigned bA[5], bB[5];
#pragma unroll
      for(int k=0;k<5;k++){ bA[k]=0xFFFFFFFFu; bB[k]=0xFFFFFFFFu; }

      __syncthreads();   // staging complete

      half8 JT[4];
#define TILE(TT, SQV, LIST) { \
      const int rl_ = (TT)*16 + col; \
      const int sw_ = rl_ & 7; \
      JT[0] = *(const half8*)(jHi + (rl_*8 + ( kg      ^ sw_))*8); \
      JT[1] = *(const half8*)(jHi + (rl_*8 + ((kg + 4) ^ sw_))*8); \
      JT[2] = *(const half8*)(jLo + (rl_*8 + ( kg      ^ sw_))*8); \
      JT[3] = *(const half8*)(jLo + (rl_*8 + ((kg + 4) ^ sw_))*8); \
      f32x4 d_ = gram6(JT, Ih0, Ih1, Il0, Il1); \
      float sv_[4] = {SQV.x, SQV.y, SQV.z, SQV.w}; \
      const int jt0_ = jb0 + (TT)*16; \
      _Pragma("unroll") \
      for(int r_=0;r_<4;r_++){ \
        unsigned kk_ = packkey32(fmaf(-2.0f, d_[r_], sv_[r_]), jt0_+r_); \
        kk_ = (jt0_+r_==myi) ? 0xFFFFFFFFu : kk_; \
        ins5u(kk_, LIST); \
      } }

      TILE(0, sq0, bA);
      TILE(1, sq1, bB);
      TILE(2, sq2, bA);
      TILE(3, sq3, bB);
#undef TILE

      unsigned b[5];
      mergeLocal32(bA, bB, b);
      mergeStage32(b, 16);
      mergeStage32(b, 32);

      if(kg==0){
#pragma unroll
        for(int k=0;k<5;k++)
          cand[((size_t)myi*NSPLIT + split)*5 + k] = b[k];
      }
    }
    __syncthreads();   // all LDS reads done before next unit's staging / s_u overwrite
  }
}

// ======== phase B: merge 64x5 u32 candidates per row + epilogue + o_sc ========
__global__ __launch_bounds__(256) void k_nnsel(
    const float* __restrict__ x, const unsigned* __restrict__ cand,
    const float* __restrict__ msum, const float* __restrict__ max_sq,
    const float* __restrict__ deg, const float* __restrict__ sq,
    float* __restrict__ o_eq, float* __restrict__ o_sc)
{
  const int w = threadIdx.x>>6, l = threadIdx.x&63;
  const int i = blockIdx.x*4 + w;
  const unsigned* cr = cand + (size_t)i*(NSPLIT*5);   // 320 entries
  unsigned c0 = cr[l], c1 = cr[64+l], c2 = cr[128+l], c3 = cr[192+l], c4 = cr[256+l];

  int sel[5];
#pragma unroll
  for(int k=0;k<5;k++){
    unsigned d = umn(min3u(c0,c1,c2), umn(c3,c4));
#pragma unroll
    for(int o=1;o<64;o<<=1) d = umn(d, sxu(d,o));
    sel[k] = (int)(d & 0xFFFu);
    if(c0==d) c0=0xFFFFFFFFu;
    else if(c1==d) c1=0xFFFFFFFFu;
    else if(c2==d) c2=0xFFFFFFFFu;
    else if(c3==d) c3=0xFFFFFFFFu;
    else if(c4==d) c4=0xFFFFFFFFu;
  }

  float smv=0.f;
#pragma unroll
  for(int k=0;k<5;k++) smv += x[(size_t)sel[k]*DD + l];
  float xiv = x[(size_t)i*DD + l];
  float lv = xiv - smv*0.2f;
  float gv = xiv - msum[l]*(1.0f/NN);
  float pl = lv*lv, pg = gv*gv;
#pragma unroll
  for(int o=1;o<64;o<<=1){ pl += __shfl_xor(pl,o,64); pg += __shfl_xor(pg,o,64); }
  if(l==0){
    o_eq[i] = 0.6f*sqrtf(pg) + 0.4f*sqrtf(pl);
    o_sc[i] = 0.5f*deg[i]/(float)(NN-1) + 0.5f*sqrtf(sq[i])/sqrtf(max_sq[0]);
  }
}

extern "C" void kernel_launch(void* const* d_in, const int* in_sizes, int n_in,
                              void* d_out, int out_size, void* d_ws, size_t ws_size,
                              hipStream_t stream) {
  const float* x = (const float*)d_in[0];
  const float* A = (const float*)d_in[1];
  float* out = (float*)d_out;
  float* ws  = (float*)d_ws;
  // ws layout (float offsets)
  float*     sq        = ws;                        // 0..4096
  float*     msum      = ws + 4096;                 // 64
  float*     max_sq    = ws + 4160;                 // 1 (pad to 4224)
  float*     deg       = ws + 4224;                 // 4096
  float*     msum_part = ws + 8320;                 // 256*64
  float*     maxsq_part= ws + 24704;                // 256
  unsigned*  counter   = (unsigned*)(ws + 24960);   // 1 (pad to 25024)
  _Float16*  xh        = (_Float16*)(ws + 25024);   // 262144 halves
  _Float16*  xl        = (_Float16*)(ws + 156096);  // 262144 halves
  unsigned*  cand      = (unsigned*)(ws + 287168);  // 4096*64*5 u32 = 5.24MB

  k_prec<<<NN/16, 256, 0, stream>>>(x, sq, xh, xl, msum_part, maxsq_part, counter);
  // persistent: 2048 blocks (8/CU, full 32-wave residency) pull 5121 units
  // from the atomic counter (unit 0 = reducer; t%5==0 sparse; else knng).
  k_mega<<<2048, 256, 0, stream>>>(x, A, sq, xh, xl, cand, counter,
                                   msum_part, maxsq_part, msum, max_sq, deg,
                                   out, out+NN, out+4*NN, out+5*NN, out+6*NN);
  k_nnsel<<<NN/4, 256, 0, stream>>>(x, cand, msum, max_sq, deg, sq,
                                    out+2*NN, out+3*NN);
}

// Round 19
// 56.574 us; speedup vs baseline: 1.9759x; 1.9759x over previous
//
#include <hip/hip_runtime.h>
#include <math.h>

#define NN 4096
#define DD 64
#define NSPLIT 64
#define JW 64

typedef _Float16 half8 __attribute__((ext_vector_type(8)));
typedef float f32x4 __attribute__((ext_vector_type(4)));

__device__ __forceinline__ unsigned sxu(unsigned v, int o){
  return (unsigned)__shfl_xor((int)v, o, 64);
}
__device__ __forceinline__ unsigned umn(unsigned a, unsigned b){ return a<b?a:b; }
__device__ __forceinline__ unsigned umx(unsigned a, unsigned b){ return a<b?b:a; }
__device__ __forceinline__ unsigned med3u(unsigned a, unsigned b, unsigned c){
  unsigned r; asm("v_med3_u32 %0, %1, %2, %3" : "=v"(r) : "v"(a), "v"(b), "v"(c)); return r;
}
__device__ __forceinline__ unsigned min3u(unsigned a, unsigned b, unsigned c){
  unsigned r; asm("v_min3_u32 %0, %1, %2, %3" : "=v"(r) : "v"(a), "v"(b), "v"(c)); return r;
}

// key = (quantized m << 12) | j ; m=sqj-2dot, q=(m+256)*2048 clamped to 20 bits
__device__ __forceinline__ unsigned packkey32(float m, int j){
  float q = fmaf(m, 2048.f, 524288.f);
  q = fminf(fmaxf(q, 0.f), 1048575.f);
  return (((unsigned)q) << 12) | (unsigned)j;
}

// sorted-5 insert via med3: b0'=min(k,b0); bi'=med3(k,b[i-1],b[i])
__device__ __forceinline__ void ins5u(unsigned k, unsigned b[5]){
  unsigned nb0 = umn(k, b[0]);
  b[4] = med3u(k, b[3], b[4]);
  b[3] = med3u(k, b[2], b[3]);
  b[2] = med3u(k, b[1], b[2]);
  b[1] = med3u(k, b[0], b[1]);
  b[0] = nb0;
}

// butterfly merge stage across lanes: sorted-5 + partner sorted-5 -> sorted-5
__device__ __forceinline__ void mergeStage32(unsigned b[5], int st){
  unsigned p0=sxu(b[0],st),p1=sxu(b[1],st),p2=sxu(b[2],st),p3=sxu(b[3],st),p4=sxu(b[4],st);
  unsigned o0=umn(b[0],p0);
  unsigned o1=min3u(b[1],p1, umx(b[0],p0));
  unsigned o2=min3u(b[2],p2, umn(umx(b[0],p1),umx(b[1],p0)));
  unsigned o3=min3u(b[3],p3, min3u(umx(b[0],p2), umx(b[1],p1), umx(b[2],p0)));
  unsigned o4=min3u(b[4],p4, umn(umn(umx(b[0],p3),umx(b[1],p2)),
                                 umn(umx(b[2],p1),umx(b[3],p0))));
  b[0]=o0;b[1]=o1;b[2]=o2;b[3]=o3;b[4]=o4;
}

// ---- fused pre: sq, split-f16 hi/lo, per-block partial colsum + max (NO atomics) ----
__global__ __launch_bounds__(256) void k_prec(const float* __restrict__ x,
                      float* __restrict__ sq,
                      _Float16* __restrict__ xh, _Float16* __restrict__ xl,
                      float* __restrict__ msum_part, float* __restrict__ maxsq_part){
  __shared__ float part[4][64];
  __shared__ float mxp[4];
  const int w = threadIdx.x>>6, lane = threadIdx.x&63;
  const int n0 = blockIdx.x*16 + w*4;
  float v0 = x[(size_t)(n0+0)*DD + lane];
  float v1 = x[(size_t)(n0+1)*DD + lane];
  float v2 = x[(size_t)(n0+2)*DD + lane];
  float v3 = x[(size_t)(n0+3)*DD + lane];
  float s0=v0*v0, s1=v1*v1, s2=v2*v2, s3=v3*v3;
#pragma unroll
  for(int o=1;o<64;o<<=1){
    s0 += __shfl_xor(s0,o,64); s1 += __shfl_xor(s1,o,64);
    s2 += __shfl_xor(s2,o,64); s3 += __shfl_xor(s3,o,64);
  }
  float vv[4] = {v0,v1,v2,v3};
  float ss[4] = {s0,s1,s2,s3};
#pragma unroll
  for(int q=0;q<4;q++){
    float v = vv[q];
    _Float16 h = (_Float16)v;
    _Float16 l = (_Float16)(v - (float)h);
    xh[(size_t)(n0+q)*DD+lane] = h;
    xl[(size_t)(n0+q)*DD+lane] = l;
    if(lane==0) sq[n0+q]=ss[q];
  }
  if(lane==0) mxp[w] = fmaxf(fmaxf(s0,s1), fmaxf(s2,s3));
  part[w][lane] = v0+v1+v2+v3; __syncthreads();
  if(w==0){
    msum_part[blockIdx.x*64 + lane] = part[0][lane]+part[1][lane]+part[2][lane]+part[3][lane];
    if(lane==0) maxsq_part[blockIdx.x] = fmaxf(fmaxf(mxp[0],mxp[1]), fmaxf(mxp[2],mxp[3]));
  }
}

// 6-MFMA split-f16 Gram for one 16x16 tile: returns row-dots for this lane
__device__ __forceinline__ f32x4 gram6(const half8 J[4],
    half8 Ih0, half8 Ih1, half8 Il0, half8 Il1){
  const f32x4 z = {0.f,0.f,0.f,0.f};
  f32x4 a1 = __builtin_amdgcn_mfma_f32_16x16x32_f16(J[0], Ih0, z, 0,0,0);
  f32x4 a2 = __builtin_amdgcn_mfma_f32_16x16x32_f16(J[2], Ih0, z, 0,0,0);
  a1 = __builtin_amdgcn_mfma_f32_16x16x32_f16(J[1], Ih1, a1, 0,0,0);
  a2 = __builtin_amdgcn_mfma_f32_16x16x32_f16(J[3], Ih1, a2, 0,0,0);
  a1 = __builtin_amdgcn_mfma_f32_16x16x32_f16(J[0], Il0, a1, 0,0,0);
  a1 = __builtin_amdgcn_mfma_f32_16x16x32_f16(J[1], Il1, a1, 0,0,0);
  return a1 + a2;
}

// ======== MEGA: bid0 = stats reduce; then 1/3 sparse, 2/3 MFMA kNN (2 strips/wave) ========
// Branch LDS union (16 KB): knng jHi[8KB]|jLo[8KB]; sparse nbr[2KB]|Sval[2KB]; reducer rr|rm
__global__ __launch_bounds__(256, 4) void k_mega(
    const float* __restrict__ x, const float* __restrict__ A,
    const float* __restrict__ sq,
    const _Float16* __restrict__ xh, const _Float16* __restrict__ xl,
    unsigned* __restrict__ cand,
    const float* __restrict__ msum_part, const float* __restrict__ maxsq_part,
    float* __restrict__ msum, float* __restrict__ max_sq, float* __restrict__ deg_out,
    float* __restrict__ o_te, float* __restrict__ o_ent,
    float* __restrict__ o_if, float* __restrict__ o_st, float* __restrict__ o_cv)
{
  __shared__ __align__(16) char smem[16384];
  const int bid = blockIdx.x;
  const int tid = threadIdx.x;
  const int w = tid>>6, lane = tid&63;

  if(bid == 0){
    float* rr = (float*)smem;              // [4][64]
    float* rm = (float*)(smem + 1024);     // [4]
    float s = 0.f;
    for(int p=w; p<256; p+=4) s += msum_part[p*64 + lane];
    rr[w*64 + lane] = s;
    float m = maxsq_part[w*64 + lane];
#pragma unroll
    for(int o=1;o<64;o<<=1) m = fmaxf(m, __shfl_xor(m,o,64));
    if(lane==0) rm[w] = m;
    __syncthreads();
    if(w==0){
      msum[lane] = rr[0*64+lane]+rr[1*64+lane]+rr[2*64+lane]+rr[3*64+lane];
      if(lane==0) max_sq[0] = fmaxf(fmaxf(rm[0],rm[1]), fmaxf(rm[2],rm[3]));
    }
    return;
  }

  const int t = bid - 1;
  if(t % 3 == 0){
    // ================= sparse branch: wave per node, ballot compaction =================
    int*   nbrw  = (int*)smem + w*128;             // [128]
    float* Svalw = (float*)(smem + 2048) + w*128;  // [128]
    const int i = (t/3)*4 + w;
    const float xid = x[(size_t)i*DD + lane];
    const float sqi = sq[i];
    const float eni = sqrtf(sqi);
    const float4* A4 = (const float4*)(A + (size_t)i*NN);
    const unsigned long long below = (1ull << lane) - 1ull;

    int base = 0;
#define COMPACT(VAL, JJ) { \
    bool p_ = (VAL) > 0.f; \
    unsigned long long m_ = __ballot(p_); \
    int ofs_ = base + (int)__popcll(m_ & below); \
    if(p_ && ofs_ < 128) nbrw[ofs_] = (JJ); \
    base += (int)__popcll(m_); \
  }
    for(int ch=0; ch<4; ++ch){
      float4 av[4];
#pragma unroll
      for(int qq=0; qq<4; ++qq) av[qq] = A4[lane + 64*(ch*4+qq)];
#pragma unroll
      for(int qq=0; qq<4; ++qq){
        int jb = 4*(lane + 64*(ch*4+qq));
        COMPACT(av[qq].x, jb+0);
        COMPACT(av[qq].y, jb+1);
        COMPACT(av[qq].z, jb+2);
        COMPACT(av[qq].w, jb+3);
      }
    }
#undef COMPACT
    const int deg = base;

    const float degf = (float)deg;
    const int dmax = min(deg, 128);
    float nb_d=0.f, ex2_d=0.f, s_d=0.f, ssq=0.f;

    for(int c0=0; c0<dmax; c0+=8){
      int jq[8]; float aq[8], qq[8];
#pragma unroll
      for(int q=0;q<8;q++) jq[q] = nbrw[min(c0+q, dmax-1)];
#pragma unroll
      for(int q=0;q<8;q++) aq[q] = x[(size_t)jq[q]*DD + lane];
#pragma unroll
      for(int q=0;q<8;q++) qq[q] = sq[jq[q]];
      asm volatile("" :: "v"(aq[0]), "v"(aq[1]), "v"(aq[2]), "v"(aq[3]),
                         "v"(aq[4]), "v"(aq[5]), "v"(aq[6]), "v"(aq[7]));
      float p[8];
#pragma unroll
      for(int q=0;q<8;q++) p[q] = xid*aq[q];
#pragma unroll
      for(int o=1;o<64;o<<=1){
#pragma unroll
        for(int q=0;q<8;q++) p[q] += __shfl_xor(p[q],o,64);
      }
#pragma unroll
      for(int q=0;q<8;q++){
        const bool valid = (c0+q) < deg;
        float c2 = fmaxf(sqi + qq[q] - 2.0f*p[q], 1e-12f);
        float inv = 1.0f/fmaxf(sqrtf(c2), 1e-8f);
        nb_d  += valid ? aq[q] : 0.f;
        ex2_d += valid ? aq[q]*aq[q] : 0.f;
        s_d   += valid ? (aq[q]-xid)*inv : 0.f;
        ssq   += valid ? c2*inv*inv : 0.f;
        if(valid && lane==q) Svalw[c0+q] = p[q]/(eni*sqrtf(qq[q]));
      }
    }

    float t0 = xid*nb_d;
    float m1 = nb_d/degf;
    float t1 = (ex2_d - degf*m1*m1)/(degf-1.0f);
    float t2 = s_d*s_d;
    float t3 = 0.f, t4 = 0.f;
    for(int s=lane; s<dmax; s+=64){ float v=Svalw[s]; t3 += expf(v); t4 += v; }
#pragma unroll
    for(int o=1;o<64;o<<=1){
      t0 += __shfl_xor(t0,o,64); t1 += __shfl_xor(t1,o,64); t2 += __shfl_xor(t2,o,64);
      t3 += __shfl_xor(t3,o,64); t4 += __shfl_xor(t4,o,64);
    }
    const float pot = t0, varm = t1*(1.0f/DD), s2 = t2, se = t3, ms = t4/degf;

    float e0=0.f, e1=0.f;
    const float inv_se = 1.0f/se;
    for(int s=lane; s<dmax; s+=64){
      float v = Svalw[s];
      float pp = expf(v)*inv_se;
      e0 -= pp*logf(pp + 1e-8f);
      float dv = v-ms; e1 += dv*dv;
    }
#pragma unroll
    for(int o=1;o<64;o<<=1){ e0 += __shfl_xor(e0,o,64); e1 += __shfl_xor(e1,o,64); }

    if(lane==0){
      o_te[i]  = sqi - pot/(degf + 1e-8f);
      o_ent[i] = e0;
      o_if[i]  = e1/(degf-1.0f);
      o_st[i]  = 1.0f/(1.0f + varm);
      o_cv[i]  = 1.0f - (s2 - ssq)/(degf*(degf-1.0f));
      deg_out[i] = degf;
    }
  } else {
    // ==== knng branch: 2 i-strips per wave share one staged 64-j chunk ====
    _Float16* jHi = (_Float16*)smem;            // 512*8 halves = 8KB
    _Float16* jLo = (_Float16*)(smem + 8192);   // 8KB
    const int kid = (t/3)*2 + (t%3) - 1;           // 0..2047
    const int split = kid & (NSPLIT-1);            // 0..63
    const int sg = kid >> 6;                       // 0..31
    const int stripA = sg*8 + w, stripB = sg*8 + w + 4;
    const int ibaseA = stripA*16, ibaseB = stripB*16;
    const int j0 = split*JW;
    const int col = lane & 15, kg = lane >> 4;
    const int vo = col*DD + kg*8;
    const int myiA = ibaseA + col, myiB = ibaseB + col;

    // stage 64 j-rows hi/lo into LDS; linear dest,
    // source pre-swizzled (granule g: row=g>>3, chunk=(g&7)^(row&7))
#pragma unroll
    for(int q_=0;q_<2;q_++){
      int g_ = q_*256 + tid;
      int r_ = g_ >> 3;
      int c_ = (g_ & 7) ^ (r_ & 7);
      const _Float16* sH_ = xh + (size_t)(j0 + r_)*DD + c_*8;
      const _Float16* sL_ = xl + (size_t)(j0 + r_)*DD + c_*8;
      __builtin_amdgcn_global_load_lds(
        (const __attribute__((address_space(1))) unsigned int*)sH_,
        (__attribute__((address_space(3))) unsigned int*)(jHi + g_*8), 16, 0, 0);
      __builtin_amdgcn_global_load_lds(
        (const __attribute__((address_space(1))) unsigned int*)sL_,
        (__attribute__((address_space(3))) unsigned int*)(jLo + g_*8), 16, 0, 0);
    }

    // I-fragments for both strips (overlap with async staging)
    const _Float16* pihA = xh + (size_t)ibaseA*DD + vo;
    const _Float16* pilA = xl + (size_t)ibaseA*DD + vo;
    const half8 IhA0 = *(const half8*)(pihA);
    const half8 IhA1 = *(const half8*)(pihA+32);
    const half8 IlA0 = *(const half8*)(pilA);
    const half8 IlA1 = *(const half8*)(pilA+32);
    const _Float16* pihB = xh + (size_t)ibaseB*DD + vo;
    const _Float16* pilB = xl + (size_t)ibaseB*DD + vo;
    const half8 IhB0 = *(const half8*)(pihB);
    const half8 IhB1 = *(const half8*)(pihB+32);
    const half8 IlB0 = *(const half8*)(pilB);
    const half8 IlB1 = *(const half8*)(pilB+32);

    const int jb0 = j0 + kg*4;
    float4 sq0 = *(const float4*)(sq + jb0);
    float4 sq1 = *(const float4*)(sq + jb0 + 16);
    float4 sq2 = *(const float4*)(sq + jb0 + 32);
    float4 sq3 = *(const float4*)(sq + jb0 + 48);

    unsigned bA[5], bB[5];
#pragma unroll
    for(int k=0;k<5;k++){ bA[k]=0xFFFFFFFFu; bB[k]=0xFFFFFFFFu; }

    __syncthreads();   // staging complete

    half8 JT[4];
#define TILE(TT, SQV) { \
    const int rl_ = (TT)*16 + col; \
    const int sw_ = rl_ & 7; \
    JT[0] = *(const half8*)(jHi + (rl_*8 + ( kg      ^ sw_))*8); \
    JT[1] = *(const half8*)(jHi + (rl_*8 + ((kg + 4) ^ sw_))*8); \
    JT[2] = *(const half8*)(jLo + (rl_*8 + ( kg      ^ sw_))*8); \
    JT[3] = *(const half8*)(jLo + (rl_*8 + ((kg + 4) ^ sw_))*8); \
    f32x4 dA_ = gram6(JT, IhA0, IhA1, IlA0, IlA1); \
    f32x4 dB_ = gram6(JT, IhB0, IhB1, IlB0, IlB1); \
    float sv_[4] = {SQV.x, SQV.y, SQV.z, SQV.w}; \
    const int jt0_ = jb0 + (TT)*16; \
    _Pragma("unroll") \
    for(int r_=0;r_<4;r_++){ \
      unsigned kA_ = packkey32(fmaf(-2.0f, dA_[r_], sv_[r_]), jt0_+r_); \
      kA_ = (jt0_+r_==myiA) ? 0xFFFFFFFFu : kA_; \
      ins5u(kA_, bA); \
      unsigned kB_ = packkey32(fmaf(-2.0f, dB_[r_], sv_[r_]), jt0_+r_); \
      kB_ = (jt0_+r_==myiB) ? 0xFFFFFFFFu : kB_; \
      ins5u(kB_, bB); \
    } }

    TILE(0, sq0);
    TILE(1, sq1);
    TILE(2, sq2);
    TILE(3, sq3);
#undef TILE

    mergeStage32(bA, 16);
    mergeStage32(bA, 32);
    mergeStage32(bB, 16);
    mergeStage32(bB, 32);

    if(kg==0){
#pragma unroll
      for(int k=0;k<5;k++){
        cand[((size_t)myiA*NSPLIT + split)*5 + k] = bA[k];
        cand[((size_t)myiB*NSPLIT + split)*5 + k] = bB[k];
      }
    }
  }
}

// ======== phase B: merge 64x5 u32 candidates per row + epilogue + o_sc ========
__global__ __launch_bounds__(256) void k_nnsel(
    const float* __restrict__ x, const unsigned* __restrict__ cand,
    const float* __restrict__ msum, const float* __restrict__ max_sq,
    const float* __restrict__ deg, const float* __restrict__ sq,
    float* __restrict__ o_eq, float* __restrict__ o_sc)
{
  const int w = threadIdx.x>>6, l = threadIdx.x&63;
  const int i = blockIdx.x*4 + w;
  const unsigned* cr = cand + (size_t)i*(NSPLIT*5);   // 320 entries
  unsigned c0 = cr[l], c1 = cr[64+l], c2 = cr[128+l], c3 = cr[192+l], c4 = cr[256+l];

  int sel[5];
#pragma unroll
  for(int k=0;k<5;k++){
    unsigned d = umn(min3u(c0,c1,c2), umn(c3,c4));
#pragma unroll
    for(int o=1;o<64;o<<=1) d = umn(d, sxu(d,o));
    sel[k] = (int)(d & 0xFFFu);
    if(c0==d) c0=0xFFFFFFFFu;
    else if(c1==d) c1=0xFFFFFFFFu;
    else if(c2==d) c2=0xFFFFFFFFu;
    else if(c3==d) c3=0xFFFFFFFFu;
    else if(c4==d) c4=0xFFFFFFFFu;
  }

  float smv=0.f;
#pragma unroll
  for(int k=0;k<5;k++) smv += x[(size_t)sel[k]*DD + l];
  float xiv = x[(size_t)i*DD + l];
  float lv = xiv - smv*0.2f;
  float gv = xiv - msum[l]*(1.0f/NN);
  float pl = lv*lv, pg = gv*gv;
#pragma unroll
  for(int o=1;o<64;o<<=1){ pl += __shfl_xor(pl,o,64); pg += __shfl_xor(pg,o,64); }
  if(l==0){
    o_eq[i] = 0.6f*sqrtf(pg) + 0.4f*sqrtf(pl);
    o_sc[i] = 0.5f*deg[i]/(float)(NN-1) + 0.5f*sqrtf(sq[i])/sqrtf(max_sq[0]);
  }
}

extern "C" void kernel_launch(void* const* d_in, const int* in_sizes, int n_in,
                              void* d_out, int out_size, void* d_ws, size_t ws_size,
                              hipStream_t stream) {
  const float* x = (const float*)d_in[0];
  const float* A = (const float*)d_in[1];
  float* out = (float*)d_out;
  float* ws  = (float*)d_ws;
  // ws layout (float offsets)
  float*     sq        = ws;                        // 0..4096
  float*     msum      = ws + 4096;                 // 64
  float*     max_sq    = ws + 4160;                 // 1 (pad to 4224)
  float*     deg       = ws + 4224;                 // 4096
  float*     msum_part = ws + 8320;                 // 256*64
  float*     maxsq_part= ws + 24704;                // 256
  _Float16*  xh        = (_Float16*)(ws + 24960);   // 262144 halves
  _Float16*  xl        = (_Float16*)(ws + 156032);  // 262144 halves
  unsigned*  cand      = (unsigned*)(ws + 287104);  // 4096*64*5 u32

  k_prec<<<NN/16, 256, 0, stream>>>(x, sq, xh, xl, msum_part, maxsq_part);
  // sparse: t%3==0 -> 1024 blocks; knng: kid=(t/3)*2+(t%3)-1 in 0..2047
  //   (32 strip-groups x 8 strips, 2 strips/wave x 64 splits); +1 reducer = 3073
  k_mega<<<3*NN/4 + 1, 256, 0, stream>>>(x, A, sq, xh, xl, cand,
                                         msum_part, maxsq_part, msum, max_sq, deg,
                                         out, out+NN, out+4*NN, out+5*NN, out+6*NN);
  k_nnsel<<<NN/4, 256, 0, stream>>>(x, cand, msum, max_sq, deg, sq,
                                    out+2*NN, out+3*NN);
}